// Round 3
// 451.139 us; speedup vs baseline: 1.0099x; 1.0099x over previous
//
#include <hip/hip_runtime.h>

#define EPSV 0.2f
#define USER_NUM 100000
#define ITEM_NUM 50000
#define NTOT 150000
#define NNZ_CNT 1200000
#define EMB 64

// clang ext_vector_types: valid operands for __builtin_nontemporal_load/store
// (HIP's float4/int2 are C++ classes and are rejected by the builtin).
typedef float v4f __attribute__((ext_vector_type(4)));
typedef int   v2i __attribute__((ext_vector_type(2)));

// ---- CSR build (3 kernels, no global scan) ----

// Pass 1: degree histogram + per-edge ticket (order within its row).
__global__ void hist_kernel(const int* __restrict__ rows,
                            int* __restrict__ hist,
                            int* __restrict__ ticket) {
    int e = blockIdx.x * blockDim.x + threadIdx.x;
    if (e < NNZ_CNT) ticket[e] = atomicAdd(&hist[rows[e]], 1);
}

// Pass 2: bump-allocate a contiguous slot range per row.
__global__ __launch_bounds__(1024) void alloc_kernel(const int* __restrict__ hist,
                                                     int2* __restrict__ rowrange,
                                                     int* __restrict__ cnt) {
    __shared__ int wsum[16];
    __shared__ int sbase;
    int t = threadIdx.x;
    int i = blockIdx.x * 1024 + t;
    int deg = (i < NTOT) ? hist[i] : 0;
    int lane = t & 63;
    int wid = t >> 6;
    // wave64 inclusive scan
    int inc = deg;
    #pragma unroll
    for (int off = 1; off < 64; off <<= 1) {
        int x = __shfl_up(inc, off, 64);
        if (lane >= off) inc += x;
    }
    if (lane == 63) wsum[wid] = inc;
    __syncthreads();
    if (t < 16) {
        int v = wsum[t];
        #pragma unroll
        for (int off = 1; off < 16; off <<= 1) {
            int x = __shfl_up(v, off, 64);
            if (t >= off) v += x;
        }
        wsum[t] = v;  // inclusive scan of wave sums
        if (t == 15) sbase = atomicAdd(cnt, v);
    }
    __syncthreads();
    int waveoff = (wid > 0) ? wsum[wid - 1] : 0;
    int excl = sbase + waveoff + inc - deg;
    if (i < NTOT) rowrange[i] = make_int2(excl, excl + deg);
}

// Pass 3: scatter edges into their slots (one 8B packed store per edge).
__global__ void build_kernel(const int* __restrict__ rows,
                             const int* __restrict__ cols,
                             const float* __restrict__ vals,
                             const int2* __restrict__ rowrange,
                             const int* __restrict__ ticket,
                             int2* __restrict__ csr) {
    int e = blockIdx.x * blockDim.x + threadIdx.x;
    if (e >= NNZ_CNT) return;
    int r = rows[e];
    int slot = rowrange[r].x + ticket[e];
    csr[slot] = make_int2(cols[e], __float_as_int(vals[e]));
}

// ---- Gather SpMM fused with perturbation / accumulation ----
// 4 rows per wave: lane = (rsub<<4)|q, q = float4 index within the 64-elem row.
// 8-edge batch per row -> 32 independent 256B gathers in flight per wave.
// FINAL_MODE (layer 2): epilogue computes final = (e1 + e2 + y)/3 instead of
// the old per-layer read-modify-write of the accumulator (saves 76.8 MB DRAM).
// Streaming traffic (noise, csr, e1, final store) uses nontemporal hints so the
// per-XCD L2 keeps the 38.4 MB gather working set instead of stream garbage.
template <bool CONCAT, bool FINAL_MODE>
__global__ void spmm_perturb_kernel(const float* __restrict__ src,
                                    const float* __restrict__ user_emb,
                                    const float* __restrict__ item_emb,
                                    const int2* __restrict__ rowrange,
                                    const int2* __restrict__ csr,
                                    const float* __restrict__ noise_k,
                                    const float* __restrict__ e1,
                                    const float* __restrict__ e2,
                                    float* __restrict__ out) {
    int wid = threadIdx.x >> 6;        // wave in block: 0..3
    int lane = threadIdx.x & 63;
    int rsub = lane >> 4;              // 0..3 : row within wave
    int q = lane & 15;                 // float4 slot within row
    int row = blockIdx.x * 16 + wid * 4 + rsub;
    if (row >= NTOT) return;
    int2 rr = rowrange[row];
    int beg = rr.x, end = rr.y;
    size_t rowoff = (size_t)row * EMB;
    // streaming loads issued early (latency overlaps the gather loop)
    v4f nv = __builtin_nontemporal_load((const v4f*)(noise_k + rowoff) + q);
    v4f a1 = (v4f)(0.f);
    v4f a2 = (v4f)(0.f);
    if constexpr (FINAL_MODE) {
        a1 = __builtin_nontemporal_load((const v4f*)(e1 + rowoff) + q);  // not gathered again
        a2 = ((const v4f*)(e2 + rowoff))[q];  // cached: doubles as gather prefetch
    }
    v4f acc = (v4f)(0.f);
    for (int j = beg; j < end; j += 8) {
        int cb[8];
        float vb[8];
        #pragma unroll
        for (int u = 0; u < 8; ++u) {
            int jj = j + u;
            int idx = (jj < end) ? jj : (end - 1);  // pad lands on in-flight batch line
            v2i ee = __builtin_nontemporal_load((const v2i*)csr + idx);
            cb[u] = ee.x;
            vb[u] = (jj < end) ? __int_as_float(ee.y) : 0.f;
        }
        #pragma unroll
        for (int u = 0; u < 8; ++u) {
            int c = cb[u];
            const float* base;
            if (CONCAT)
                base = (c < USER_NUM) ? (user_emb + (size_t)c * EMB)
                                      : (item_emb + (size_t)(c - USER_NUM) * EMB);
            else
                base = src + (size_t)c * EMB;
            v4f x = ((const v4f*)base)[q];
            acc.x = fmaf(vb[u], x.x, acc.x);
            acc.y = fmaf(vb[u], x.y, acc.y);
            acc.z = fmaf(vb[u], x.z, acc.z);
            acc.w = fmaf(vb[u], x.w, acc.w);
        }
    }
    // ||noise_row|| over the 16 lanes of this row group (xor 8,4,2,1 stays in-group)
    float s = nv.x * nv.x + nv.y * nv.y + nv.z * nv.z + nv.w * nv.w;
    #pragma unroll
    for (int off = 8; off > 0; off >>= 1) s += __shfl_xor(s, off, 64);
    float scale = EPSV / fmaxf(sqrtf(s), 1e-12f);
    auto pert = [&](float a, float n) {
        float sg = (a > 0.f) ? 1.f : ((a < 0.f) ? -1.f : 0.f);
        return fmaf(sg * scale, n, a);
    };
    v4f y;
    y.x = pert(acc.x, nv.x);
    y.y = pert(acc.y, nv.y);
    y.z = pert(acc.z, nv.z);
    y.w = pert(acc.w, nv.w);
    if constexpr (FINAL_MODE) {
        const float third = 1.f / 3.f;
        v4f f = (a1 + a2 + y) * third;
        __builtin_nontemporal_store(f, (v4f*)(out + rowoff) + q);  // never re-read
    } else {
        ((v4f*)(out + rowoff))[q] = y;  // cached: next layer gathers from this
    }
}

extern "C" void kernel_launch(void* const* d_in, const int* in_sizes, int n_in,
                              void* d_out, int out_size, void* d_ws, size_t ws_size,
                              hipStream_t stream) {
    const float* user_emb = (const float*)d_in[0];
    const float* item_emb = (const float*)d_in[1];
    const int*   adj_rows = (const int*)d_in[2];
    const int*   adj_cols = (const int*)d_in[3];
    const float* adj_vals = (const float*)d_in[4];
    const float* noise    = (const float*)d_in[5];

    float* out_final = (float*)d_out;                       // N x 64
    float* out_cl    = (float*)d_out + (size_t)NTOT * EMB;  // N x 64 (== ego after layer 0)

    // ws layout
    char* p = (char*)d_ws;
    float* wsA      = (float*)p;  p += (size_t)NTOT * EMB * sizeof(float); // 38.4 MB
    int2*  rowrange = (int2*)p;   p += (size_t)NTOT * sizeof(int2);        // 1.2 MB
    int2*  csr      = (int2*)p;   p += (size_t)NNZ_CNT * sizeof(int2);     // 9.6 MB
    int*   ticket   = (int*)p;    p += (size_t)NNZ_CNT * sizeof(int);      // 4.8 MB
    int*   hist     = (int*)p;    p += (size_t)NTOT * sizeof(int);         // 0.6 MB
    int*   cnt      = (int*)p;    p += 16 * sizeof(int);

    // zero hist + cnt in ONE memset (they're adjacent)
    (void)hipMemsetAsync(hist, 0, ((size_t)NTOT + 16) * sizeof(int), stream);

    hist_kernel<<<(NNZ_CNT + 255) / 256, 256, 0, stream>>>(adj_rows, hist, ticket);
    alloc_kernel<<<(NTOT + 1023) / 1024, 1024, 0, stream>>>(hist, rowrange, cnt);
    build_kernel<<<(NNZ_CNT + 255) / 256, 256, 0, stream>>>(
        adj_rows, adj_cols, adj_vals, rowrange, ticket, csr);

    const int spmm_blocks = (NTOT + 15) / 16;
    const size_t NE = (size_t)NTOT * EMB;

    // layer 0: src = concat(user,item) virtual -> ego1 to out_cl (cl output)
    spmm_perturb_kernel<true, false><<<spmm_blocks, 256, 0, stream>>>(
        nullptr, user_emb, item_emb, rowrange, csr, noise + 0 * NE,
        nullptr, nullptr, out_cl);
    // layer 1: src = out_cl -> ego2 to wsA
    spmm_perturb_kernel<false, false><<<spmm_blocks, 256, 0, stream>>>(
        out_cl, nullptr, nullptr, rowrange, csr, noise + 1 * NE,
        nullptr, nullptr, wsA);
    // layer 2: src = wsA -> y2; final = (ego1 + ego2 + y2)/3
    spmm_perturb_kernel<false, true><<<spmm_blocks, 256, 0, stream>>>(
        wsA, nullptr, nullptr, rowrange, csr, noise + 2 * NE,
        out_cl, wsA, out_final);
}